// Round 2
// baseline (1515.109 us; speedup 1.0000x reference)
//
#include <hip/hip_runtime.h>

#define N_NODES 100000
#define N_PAD 100032      // padded to 64-node tiles for MFMA sizematch
#define N_EDGES 1600000
#define NUM_RELS 8
#define KDIM 256      // E_DIM * MAX_LEN
#define HD 64
#define KF 512        // fused GEMM K = NUM_RELS * 64

// CSR-build partition parameters: 256-node coarse buckets
#define B_SHIFT 8
#define NBUCK 392         // ceil(100000/256)=391, +1 pad
#define NBUCK_USED 391
#define NBLK_P 512
#define TPB_P 256
#define EPB 3125          // 512 * 3125 = 1.6M exactly

typedef __attribute__((ext_vector_type(8))) short bf16x8;
typedef __attribute__((ext_vector_type(4))) float f32x4;

__device__ inline unsigned short f2bf(float f) {
    unsigned u = __float_as_uint(f);
    u += 0x7fff + ((u >> 16) & 1);   // round-to-nearest-even
    return (unsigned short)(u >> 16);
}
__device__ inline float bf2f(unsigned short s) {
    return __uint_as_float(((unsigned)s) << 16);
}
__device__ inline unsigned packtrunc(float x, float y) {
    return (__float_as_uint(x) >> 16) | (__float_as_uint(y) & 0xffff0000u);
}

// ---------------- weights:
//  WpF_l: B-fragment layout over K=512: WpF[((s*4+q)*64+o)*8+j] = Wfull[kk=s*32+q*8+j][o]
//  where Wfull[r*64+k][o] = sum_b comp[r,b] V[b,k,o]
//  smPack: B-fragment layout for size matcher (K=256)
__global__ void k_weights(const float* __restrict__ V1, const float* __restrict__ comp1,
                          const float* __restrict__ V2, const float* __restrict__ comp2,
                          const float* __restrict__ sm_w,
                          unsigned short* __restrict__ WpF1, unsigned short* __restrict__ WpF2,
                          unsigned short* __restrict__ smPack) {
    int idx = blockIdx.x * 256 + threadIdx.x;
    if (idx < 2 * NUM_RELS * 64 * 64) {
        int l = idx >> 15;
        int r = (idx >> 12) & 7;
        int k = (idx >> 6) & 63;
        int o = idx & 63;
        const float* V = l ? V2 : V1;
        const float* comp = l ? comp2 : comp1;
        float s = 0.f;
#pragma unroll
        for (int b = 0; b < 8; b++) s += comp[r * 8 + b] * V[(b * 64 + k) * 64 + o];
        int kk = r * 64 + k;
        int ss = kk >> 5, q = (kk >> 3) & 3, j = kk & 7;
        unsigned short* Wp = l ? WpF2 : WpF1;
        Wp[(((ss * 4 + q) * 64) + o) * 8 + j] = f2bf(s);
    } else {
        int j = idx - 65536;
        if (j < KDIM * HD) {
            int k = j >> 6, o = j & 63;
            int s = k >> 5, q = (k >> 3) & 3, jj = k & 7;
            smPack[(((s * 4 + q) * 64) + o) * 8 + jj] = f2bf(sm_w[o * KDIM + k]);
        }
    }
}

// ---------------- pass A: per-block LDS histogram over coarse buckets
__launch_bounds__(TPB_P)
__global__ void k_pcount(const int* __restrict__ dst, int* __restrict__ cnt) {
    __shared__ int lh[NBUCK];
    int t = threadIdx.x, blk = blockIdx.x;
    for (int b = t; b < NBUCK; b += TPB_P) lh[b] = 0;
    __syncthreads();
    int base = blk * EPB;
    for (int i = t; i < EPB; i += TPB_P) atomicAdd(&lh[dst[base + i] >> B_SHIFT], 1);
    __syncthreads();
    for (int b = t; b < NBUCK; b += TPB_P) cnt[blk * NBUCK + b] = lh[b];
}

// ---------------- pass B1: per-bucket exclusive scan across the NBLK_P blocks
__launch_bounds__(NBLK_P)
__global__ void k_pscan(const int* __restrict__ cnt, int* __restrict__ boffm, int* __restrict__ btot) {
    __shared__ int s[NBLK_P];
    int b = blockIdx.x, t = threadIdx.x;
    int v = cnt[t * NBUCK + b];
    s[t] = v;
    __syncthreads();
    for (int off = 1; off < NBLK_P; off <<= 1) {
        int u = (t >= off) ? s[t - off] : 0;
        __syncthreads();
        s[t] += u;
        __syncthreads();
    }
    boffm[t * NBUCK + b] = s[t] - v;
    if (t == NBLK_P - 1) btot[b] = s[NBLK_P - 1];
}

// ---------------- pass B2: exclusive scan over bucket totals -> bucket starts; sentinel
__launch_bounds__(512)
__global__ void k_bscan(const int* __restrict__ btot, int* __restrict__ bstart, int* __restrict__ rowptr8) {
    __shared__ int s[512];
    int t = threadIdx.x;
    int v = (t < NBUCK_USED) ? btot[t] : 0;
    s[t] = v;
    __syncthreads();
    for (int off = 1; off < 512; off <<= 1) {
        int u = (t >= off) ? s[t - off] : 0;
        __syncthreads();
        s[t] += u;
        __syncthreads();
    }
    bstart[t] = s[t] - v;
    if (t == 0) rowptr8[(size_t)N_NODES * 8] = N_EDGES;
}

// ---------------- pass C: scatter edges into bucket-contiguous staging
// packed = src | et<<17 | dlocal<<20  -> key = (packed>>17)&2047 = dlocal*8+et
__launch_bounds__(TPB_P)
__global__ void k_pscatter(const int* __restrict__ src, const int* __restrict__ dst,
                           const int* __restrict__ et, const float* __restrict__ norm,
                           const int* __restrict__ boffm, const int* __restrict__ bstart,
                           int2* __restrict__ staged) {
    __shared__ int ldsoff[NBUCK];
    int t = threadIdx.x, blk = blockIdx.x;
    for (int b = t; b < NBUCK; b += TPB_P) ldsoff[b] = bstart[b] + boffm[blk * NBUCK + b];
    __syncthreads();
    int base = blk * EPB;
    for (int i = t; i < EPB; i += TPB_P) {
        int e = base + i;
        int d = dst[e];
        int bu = d >> B_SHIFT;
        int pos = atomicAdd(&ldsoff[bu], 1);
        int packed = src[e] | (et[e] << 17) | ((d & 255) << 20);
        staged[pos] = make_int2(packed, __float_as_int(norm[e]));
    }
}

// ---------------- pass D: per-bucket 2048-bin counting sort -> rowptr8 + sorted edata
// edata keeps src | et<<17 (et needed by k_fused's rel binning)
__launch_bounds__(512)
__global__ void k_finalize(const int2* __restrict__ staged, const int* __restrict__ bstart,
                           const int* __restrict__ btot, int* __restrict__ rowptr8,
                           int2* __restrict__ edata) {
    __shared__ int lh[2048];
    __shared__ int s512[512];
    __shared__ int lsc[2048];
    int b = blockIdx.x, t = threadIdx.x;
    int base = bstart[b];
    int cnt = btot[b];
    lh[t] = 0; lh[t + 512] = 0; lh[t + 1024] = 0; lh[t + 1536] = 0;
    __syncthreads();
    int2 held[9];
    int key[9], rank[9];
    int nh = 0;
    for (int i = t; i < cnt; i += 512) {
        int2 ed = staged[base + i];
        int k = (ed.x >> 17) & 2047;
        held[nh] = ed; key[nh] = k; rank[nh] = atomicAdd(&lh[k], 1); nh++;
    }
    __syncthreads();
    int b0 = lh[t * 4], b1 = lh[t * 4 + 1], b2 = lh[t * 4 + 2], b3 = lh[t * 4 + 3];
    int tot = b0 + b1 + b2 + b3;
    s512[t] = tot;
    __syncthreads();
    for (int off = 1; off < 512; off <<= 1) {
        int u = (t >= off) ? s512[t - off] : 0;
        __syncthreads();
        s512[t] += u;
        __syncthreads();
    }
    int excl = s512[t] - tot;
    lsc[t * 4] = excl;
    lsc[t * 4 + 1] = excl + b0;
    lsc[t * 4 + 2] = excl + b0 + b1;
    lsc[t * 4 + 3] = excl + b0 + b1 + b2;
    __syncthreads();
    int limit = (N_NODES << 3) - (b << 11);
    for (int idx = t; idx < 2048; idx += 512)
        if (idx < limit) rowptr8[(b << 11) + idx] = base + lsc[idx];
    for (int i = 0; i < nh; i++) {
        int p = base + lsc[key[i]] + rank[i];
        edata[p] = make_int2(held[i].x & 0xFFFFF, held[i].y);   // src | et<<17
    }
}

// ---------------- size matcher (MFMA, no LDS)
__launch_bounds__(256)
__global__ void k_sizematch(const int* __restrict__ feat, const float* __restrict__ emb_w,
                            const unsigned short* __restrict__ smPack, const float* __restrict__ sm_b,
                            unsigned short* __restrict__ xb) {
    int t = threadIdx.x;
    int wave = t >> 6, lane = t & 63;
    int q = lane >> 4, c = lane & 15;
    int n0 = blockIdx.x * 64 + wave * 16;
    int node = n0 + c;
    int nclamp = (node < N_NODES) ? node : (N_NODES - 1);
    const int4* fr = (const int4*)(feat + (size_t)nclamp * 8);
    int4 f0 = fr[0], f1 = fr[1];
    int fidx[8] = {f0.x, f0.y, f0.z, f0.w, f1.x, f1.y, f1.z, f1.w};
    f32x4 acc[4];
#pragma unroll
    for (int i = 0; i < 4; i++) acc[i] = (f32x4){0.f, 0.f, 0.f, 0.f};
    const bf16x8* B8 = (const bf16x8*)smPack;
#pragma unroll
    for (int s = 0; s < 8; s++) {
        const float4* ar = (const float4*)(emb_w + (size_t)fidx[s] * 32 + q * 8);
        float4 a0 = ar[0], a1 = ar[1];
        union { unsigned u[4]; bf16x8 v; } A;
        A.u[0] = packtrunc(a0.x, a0.y);
        A.u[1] = packtrunc(a0.z, a0.w);
        A.u[2] = packtrunc(a1.x, a1.y);
        A.u[3] = packtrunc(a1.z, a1.w);
#pragma unroll
        for (int tl = 0; tl < 4; tl++) {
            bf16x8 b = B8[(s * 4 + q) * 64 + tl * 16 + c];
            acc[tl] = __builtin_amdgcn_mfma_f32_16x16x32_bf16(A.v, b, acc[tl], 0, 0, 0);
        }
    }
    int row_base = n0 + q * 4;
    bool full = (n0 + 15 < N_NODES);
#pragma unroll
    for (int tl = 0; tl < 4; tl++) {
        int o = tl * 16 + c;
        float bia = sm_b[o];
#pragma unroll
        for (int r = 0; r < 4; r++) {
            int nd = row_base + r;
            if (full || nd < N_NODES)
                xb[(size_t)nd * 64 + o] = f2bf(acc[tl][r] + bia);
        }
    }
}

// ---------------- fused layer: branchless ds_add_f32 aggregation + MFMA
// block: 256 thr = 4 waves; 8 nodes/block (2 per wave); grid N_NODES/8.
// Aggregation is ORDER-FREE: per-edge f32 atomicAdd into agg[row][rel*64+ch]
// (ds_add_f32, fire-and-forget). No rel-flush state machine, no data-dependent
// branches, no remainder loop: the edata chunk load is exec-masked so padded
// lanes carry ed = (0,0) -> y = 0 -> contribute nothing.
__launch_bounds__(256)
__global__ void k_fused(const unsigned short* __restrict__ xin,
                        const int* __restrict__ rowptr8, const int2* __restrict__ edata,
                        const unsigned short* __restrict__ WpF, const float* __restrict__ bias,
                        float* __restrict__ outf, unsigned short* __restrict__ outb, int mode) {
    // 516 = 512 + 4 pad: row stride 2064 B keeps MFMA-phase b128 reads ~4-way max
    __shared__ __align__(16) float agg[8][516];
    int t = threadIdx.x;
    int wave = t >> 6, lane = t & 63;
    int n0 = blockIdx.x * 8;
    // each wave zero-inits its OWN 2 rows; it is the only writer of them during
    // the edge phase, so no barrier is needed before the edge loop.
    {
        int4* z = (int4*)&agg[wave * 2][0];
        for (int i = lane; i < 258; i += 64) z[i] = make_int4(0, 0, 0, 0);
    }
    for (int ni = 0; ni < 2; ni++) {
        int lrow = wave * 2 + ni;
        int node = n0 + lrow;
        int j0 = rowptr8[(size_t)node * 8];
        int j1 = rowptr8[(size_t)node * 8 + 8];
        for (int jc = j0; jc < j1; jc += 64) {
            int m = j1 - jc; if (m > 64) m = 64;
            int2 ed = make_int2(0, 0);
            if (lane < m) ed = edata[jc + lane];   // exact-degree coalesced load
            for (int i = 0; i < m; i += 8) {
#define RL(k) int x##k = __builtin_amdgcn_readlane(ed.x, i + k); \
              int y##k = __builtin_amdgcn_readlane(ed.y, i + k);
#define LD(k) unsigned short v##k = xin[((size_t)(unsigned)(x##k & 0x1FFFF) << 6) + lane];
#define AC(k) atomicAdd(&agg[lrow][(((x##k >> 17) & 7) << 6) + lane], \
                        __int_as_float(y##k) * bf2f(v##k));
                RL(0) RL(1) RL(2) RL(3) RL(4) RL(5) RL(6) RL(7)
                LD(0) LD(1) LD(2) LD(3) LD(4) LD(5) LD(6) LD(7)
                AC(0) AC(1) AC(2) AC(3) AC(4) AC(5) AC(6) AC(7)
#undef RL
#undef LD
#undef AC
            }
        }
    }
    __syncthreads();
    // ---- MFMA: [8 nodes x 512] @ WpF -> 64 outs; wave covers cols [wave*16, +16)
    // A-tile rows 8..15 alias rows 0..7 (results discarded at store, q<2 only).
    int q = lane >> 4, c = lane & 15;
    int o16 = wave * 16;
    f32x4 accd = (f32x4){0.f, 0.f, 0.f, 0.f};
    const bf16x8* B8 = (const bf16x8*)WpF;
    const float* ar = &agg[c & 7][0];
#pragma unroll
    for (int s = 0; s < 16; s++) {
        const float4* f4 = (const float4*)(ar + s * 32 + q * 8);
        float4 lo = f4[0], hi = f4[1];
        union { unsigned u[4]; bf16x8 v; } A;
        asm("v_cvt_pk_bf16_f32 %0, %1, %2" : "=v"(A.u[0]) : "v"(lo.x), "v"(lo.y));
        asm("v_cvt_pk_bf16_f32 %0, %1, %2" : "=v"(A.u[1]) : "v"(lo.z), "v"(lo.w));
        asm("v_cvt_pk_bf16_f32 %0, %1, %2" : "=v"(A.u[2]) : "v"(hi.x), "v"(hi.y));
        asm("v_cvt_pk_bf16_f32 %0, %1, %2" : "=v"(A.u[3]) : "v"(hi.z), "v"(hi.w));
        bf16x8 bfr = B8[(s * 4 + q) * 64 + o16 + c];
        accd = __builtin_amdgcn_mfma_f32_16x16x32_bf16(A.v, bfr, accd, 0, 0, 0);
    }
    int col = o16 + c;
    float bia = bias[col];
    if (q < 2) {
#pragma unroll
        for (int r = 0; r < 4; r++) {
            int node = n0 + q * 4 + r;
            float v = accd[r] + bia;
            if (mode == 1) {
                v = fmaxf(v, 0.f);
                outb[(size_t)node * 64 + col] = f2bf(v);
            } else {
                outf[(size_t)node * 64 + col] = v;
            }
        }
    }
}

extern "C" void kernel_launch(void* const* d_in, const int* in_sizes, int n_in,
                              void* d_out, int out_size, void* d_ws, size_t ws_size,
                              hipStream_t stream) {
    const int*   feat  = (const int*)d_in[0];
    const int*   src   = (const int*)d_in[1];
    const int*   dst   = (const int*)d_in[2];
    const int*   etype = (const int*)d_in[3];
    const float* norm  = (const float*)d_in[4];
    const float* emb_w = (const float*)d_in[5];
    const float* sm_w  = (const float*)d_in[6];
    const float* sm_b  = (const float*)d_in[7];
    const float* V1    = (const float*)d_in[8];
    const float* comp1 = (const float*)d_in[9];
    const float* b1    = (const float*)d_in[10];
    const float* V2    = (const float*)d_in[11];
    const float* comp2 = (const float*)d_in[12];
    const float* b2    = (const float*)d_in[13];
    float* out = (float*)d_out;

    char* p = (char*)d_ws;
    auto alloc = [&](size_t bytes) { void* q = (void*)p; p += (bytes + 255) & ~(size_t)255; return q; };
    unsigned short* xb   = (unsigned short*)alloc((size_t)N_PAD * 64 * 2);  // 12.8 MB
    unsigned short* hb   = (unsigned short*)alloc((size_t)N_PAD * 64 * 2);  // 12.8 MB
    unsigned short* WpF1 = (unsigned short*)alloc((size_t)KF * HD * 2);     // 64 KB
    unsigned short* WpF2 = (unsigned short*)alloc((size_t)KF * HD * 2);
    unsigned short* smPack = (unsigned short*)alloc(KDIM * HD * 2);         // 32 KB
    int*   cnt    = (int*)alloc((size_t)NBLK_P * NBUCK * 4);                // 803 KB
    int*   boffm  = (int*)alloc((size_t)NBLK_P * NBUCK * 4);                // 803 KB
    int*   btot   = (int*)alloc((size_t)NBUCK * 4);
    int*   bstart = (int*)alloc((size_t)(NBUCK + 1) * 4);
    int*   rowptr8 = (int*)alloc(((size_t)N_NODES * 8 + 1) * 4);            // 3.2 MB
    int2*  staged = (int2*)alloc((size_t)N_EDGES * 8);                      // 12.8 MB
    int2*  edata  = (int2*)alloc((size_t)N_EDGES * 8);                      // 12.8 MB

    k_weights<<<320, 256, 0, stream>>>(V1, comp1, V2, comp2, sm_w, WpF1, WpF2, smPack);

    k_pcount<<<NBLK_P, TPB_P, 0, stream>>>(dst, cnt);
    k_pscan<<<NBUCK_USED, NBLK_P, 0, stream>>>(cnt, boffm, btot);
    k_bscan<<<1, 512, 0, stream>>>(btot, bstart, rowptr8);
    k_pscatter<<<NBLK_P, TPB_P, 0, stream>>>(src, dst, etype, norm, boffm, bstart, staged);
    k_finalize<<<NBUCK_USED, 512, 0, stream>>>(staged, bstart, btot, rowptr8, edata);

    k_sizematch<<<N_PAD / 64, 256, 0, stream>>>(feat, emb_w, smPack, sm_b, xb);

    k_fused<<<N_NODES / 8, 256, 0, stream>>>(xb, rowptr8, edata, WpF1, b1, nullptr, hb, 1);
    k_fused<<<N_NODES / 8, 256, 0, stream>>>(hb, rowptr8, edata, WpF2, b2, out, nullptr, 0);
}

// Round 3
// 309.784 us; speedup vs baseline: 4.8909x; 4.8909x over previous
//
#include <hip/hip_runtime.h>

#define N_NODES 100000
#define N_PAD 100032      // padded to 64-node tiles for MFMA sizematch
#define N_EDGES 1600000
#define NUM_RELS 8
#define KDIM 256      // E_DIM * MAX_LEN
#define HD 64
#define KF 512        // fused GEMM K = NUM_RELS * 64

// CSR-build partition parameters: 256-node coarse buckets
#define B_SHIFT 8
#define NBUCK 392         // ceil(100000/256)=391, +1 pad
#define NBUCK_USED 391
#define NBLK_P 512
#define TPB_P 256
#define EPB 3125          // 512 * 3125 = 1.6M exactly

typedef __attribute__((ext_vector_type(8))) short bf16x8;
typedef __attribute__((ext_vector_type(4))) float f32x4;

__device__ inline unsigned short f2bf(float f) {
    unsigned u = __float_as_uint(f);
    u += 0x7fff + ((u >> 16) & 1);   // round-to-nearest-even
    return (unsigned short)(u >> 16);
}
__device__ inline float bf2f(unsigned short s) {
    return __uint_as_float(((unsigned)s) << 16);
}
__device__ inline unsigned packtrunc(float x, float y) {
    return (__float_as_uint(x) >> 16) | (__float_as_uint(y) & 0xffff0000u);
}

// ---------------- weights:
//  WpF_l: B-fragment layout over K=512: WpF[((s*4+q)*64+o)*8+j] = Wfull[kk=s*32+q*8+j][o]
//  where Wfull[r*64+k][o] = sum_b comp[r,b] V[b,k,o]
//  smPack: B-fragment layout for size matcher (K=256)
__global__ void k_weights(const float* __restrict__ V1, const float* __restrict__ comp1,
                          const float* __restrict__ V2, const float* __restrict__ comp2,
                          const float* __restrict__ sm_w,
                          unsigned short* __restrict__ WpF1, unsigned short* __restrict__ WpF2,
                          unsigned short* __restrict__ smPack) {
    int idx = blockIdx.x * 256 + threadIdx.x;
    if (idx < 2 * NUM_RELS * 64 * 64) {
        int l = idx >> 15;
        int r = (idx >> 12) & 7;
        int k = (idx >> 6) & 63;
        int o = idx & 63;
        const float* V = l ? V2 : V1;
        const float* comp = l ? comp2 : comp1;
        float s = 0.f;
#pragma unroll
        for (int b = 0; b < 8; b++) s += comp[r * 8 + b] * V[(b * 64 + k) * 64 + o];
        int kk = r * 64 + k;
        int ss = kk >> 5, q = (kk >> 3) & 3, j = kk & 7;
        unsigned short* Wp = l ? WpF2 : WpF1;
        Wp[(((ss * 4 + q) * 64) + o) * 8 + j] = f2bf(s);
    } else {
        int j = idx - 65536;
        if (j < KDIM * HD) {
            int k = j >> 6, o = j & 63;
            int s = k >> 5, q = (k >> 3) & 3, jj = k & 7;
            smPack[(((s * 4 + q) * 64) + o) * 8 + jj] = f2bf(sm_w[o * KDIM + k]);
        }
    }
}

// ---------------- pass A: per-block LDS histogram over coarse buckets
__launch_bounds__(TPB_P)
__global__ void k_pcount(const int* __restrict__ dst, int* __restrict__ cnt) {
    __shared__ int lh[NBUCK];
    int t = threadIdx.x, blk = blockIdx.x;
    for (int b = t; b < NBUCK; b += TPB_P) lh[b] = 0;
    __syncthreads();
    int base = blk * EPB;
    for (int i = t; i < EPB; i += TPB_P) atomicAdd(&lh[dst[base + i] >> B_SHIFT], 1);
    __syncthreads();
    for (int b = t; b < NBUCK; b += TPB_P) cnt[blk * NBUCK + b] = lh[b];
}

// ---------------- pass B1: per-bucket exclusive scan across the NBLK_P blocks
__launch_bounds__(NBLK_P)
__global__ void k_pscan(const int* __restrict__ cnt, int* __restrict__ boffm, int* __restrict__ btot) {
    __shared__ int s[NBLK_P];
    int b = blockIdx.x, t = threadIdx.x;
    int v = cnt[t * NBUCK + b];
    s[t] = v;
    __syncthreads();
    for (int off = 1; off < NBLK_P; off <<= 1) {
        int u = (t >= off) ? s[t - off] : 0;
        __syncthreads();
        s[t] += u;
        __syncthreads();
    }
    boffm[t * NBUCK + b] = s[t] - v;
    if (t == NBLK_P - 1) btot[b] = s[NBLK_P - 1];
}

// ---------------- pass B2: exclusive scan over bucket totals -> bucket starts; sentinel
__launch_bounds__(512)
__global__ void k_bscan(const int* __restrict__ btot, int* __restrict__ bstart, int* __restrict__ rowptr8) {
    __shared__ int s[512];
    int t = threadIdx.x;
    int v = (t < NBUCK_USED) ? btot[t] : 0;
    s[t] = v;
    __syncthreads();
    for (int off = 1; off < 512; off <<= 1) {
        int u = (t >= off) ? s[t - off] : 0;
        __syncthreads();
        s[t] += u;
        __syncthreads();
    }
    bstart[t] = s[t] - v;
    if (t == 0) rowptr8[(size_t)N_NODES * 8] = N_EDGES;
}

// ---------------- pass C: scatter edges into bucket-contiguous staging
// packed = src | et<<17 | dlocal<<20  -> key = (packed>>17)&2047 = dlocal*8+et
__launch_bounds__(TPB_P)
__global__ void k_pscatter(const int* __restrict__ src, const int* __restrict__ dst,
                           const int* __restrict__ et, const float* __restrict__ norm,
                           const int* __restrict__ boffm, const int* __restrict__ bstart,
                           int2* __restrict__ staged) {
    __shared__ int ldsoff[NBUCK];
    int t = threadIdx.x, blk = blockIdx.x;
    for (int b = t; b < NBUCK; b += TPB_P) ldsoff[b] = bstart[b] + boffm[blk * NBUCK + b];
    __syncthreads();
    int base = blk * EPB;
    for (int i = t; i < EPB; i += TPB_P) {
        int e = base + i;
        int d = dst[e];
        int bu = d >> B_SHIFT;
        int pos = atomicAdd(&ldsoff[bu], 1);
        int packed = src[e] | (et[e] << 17) | ((d & 255) << 20);
        staged[pos] = make_int2(packed, __float_as_int(norm[e]));
    }
}

// ---------------- pass D: per-bucket 2048-bin counting sort -> rowptr8 + sorted edata
// edata keeps src | et<<17 (et needed by k_fused's flush logic)
__launch_bounds__(512)
__global__ void k_finalize(const int2* __restrict__ staged, const int* __restrict__ bstart,
                           const int* __restrict__ btot, int* __restrict__ rowptr8,
                           int2* __restrict__ edata) {
    __shared__ int lh[2048];
    __shared__ int s512[512];
    __shared__ int lsc[2048];
    int b = blockIdx.x, t = threadIdx.x;
    int base = bstart[b];
    int cnt = btot[b];
    lh[t] = 0; lh[t + 512] = 0; lh[t + 1024] = 0; lh[t + 1536] = 0;
    __syncthreads();
    int2 held[9];
    int key[9], rank[9];
    int nh = 0;
    for (int i = t; i < cnt; i += 512) {
        int2 ed = staged[base + i];
        int k = (ed.x >> 17) & 2047;
        held[nh] = ed; key[nh] = k; rank[nh] = atomicAdd(&lh[k], 1); nh++;
    }
    __syncthreads();
    int b0 = lh[t * 4], b1 = lh[t * 4 + 1], b2 = lh[t * 4 + 2], b3 = lh[t * 4 + 3];
    int tot = b0 + b1 + b2 + b3;
    s512[t] = tot;
    __syncthreads();
    for (int off = 1; off < 512; off <<= 1) {
        int u = (t >= off) ? s512[t - off] : 0;
        __syncthreads();
        s512[t] += u;
        __syncthreads();
    }
    int excl = s512[t] - tot;
    lsc[t * 4] = excl;
    lsc[t * 4 + 1] = excl + b0;
    lsc[t * 4 + 2] = excl + b0 + b1;
    lsc[t * 4 + 3] = excl + b0 + b1 + b2;
    __syncthreads();
    int limit = (N_NODES << 3) - (b << 11);
    for (int idx = t; idx < 2048; idx += 512)
        if (idx < limit) rowptr8[(b << 11) + idx] = base + lsc[idx];
    for (int i = 0; i < nh; i++) {
        int p = base + lsc[key[i]] + rank[i];
        edata[p] = make_int2(held[i].x & 0xFFFFF, held[i].y);   // src | et<<17
    }
}

// ---------------- size matcher (MFMA, no LDS)
__launch_bounds__(256)
__global__ void k_sizematch(const int* __restrict__ feat, const float* __restrict__ emb_w,
                            const unsigned short* __restrict__ smPack, const float* __restrict__ sm_b,
                            unsigned short* __restrict__ xb) {
    int t = threadIdx.x;
    int wave = t >> 6, lane = t & 63;
    int q = lane >> 4, c = lane & 15;
    int n0 = blockIdx.x * 64 + wave * 16;
    int node = n0 + c;
    int nclamp = (node < N_NODES) ? node : (N_NODES - 1);
    const int4* fr = (const int4*)(feat + (size_t)nclamp * 8);
    int4 f0 = fr[0], f1 = fr[1];
    int fidx[8] = {f0.x, f0.y, f0.z, f0.w, f1.x, f1.y, f1.z, f1.w};
    f32x4 acc[4];
#pragma unroll
    for (int i = 0; i < 4; i++) acc[i] = (f32x4){0.f, 0.f, 0.f, 0.f};
    const bf16x8* B8 = (const bf16x8*)smPack;
#pragma unroll
    for (int s = 0; s < 8; s++) {
        const float4* ar = (const float4*)(emb_w + (size_t)fidx[s] * 32 + q * 8);
        float4 a0 = ar[0], a1 = ar[1];
        union { unsigned u[4]; bf16x8 v; } A;
        A.u[0] = packtrunc(a0.x, a0.y);
        A.u[1] = packtrunc(a0.z, a0.w);
        A.u[2] = packtrunc(a1.x, a1.y);
        A.u[3] = packtrunc(a1.z, a1.w);
#pragma unroll
        for (int tl = 0; tl < 4; tl++) {
            bf16x8 b = B8[(s * 4 + q) * 64 + tl * 16 + c];
            acc[tl] = __builtin_amdgcn_mfma_f32_16x16x32_bf16(A.v, b, acc[tl], 0, 0, 0);
        }
    }
    int row_base = n0 + q * 4;
    bool full = (n0 + 15 < N_NODES);
#pragma unroll
    for (int tl = 0; tl < 4; tl++) {
        int o = tl * 16 + c;
        float bia = sm_b[o];
#pragma unroll
        for (int r = 0; r < 4; r++) {
            int nd = row_base + r;
            if (full || nd < N_NODES)
                xb[(size_t)nd * 64 + o] = f2bf(acc[tl][r] + bia);
        }
    }
}

// ---------------- fused layer: dual-stream rel-sorted flush aggregation + MFMA
// block: 256 thr = 4 waves; 16 nodes/block (4 per wave); grid N_NODES/16.
// Two nodes (A,B) are processed with fully interleaved code: both edata chunks
// resident, 16 gathers in flight per group, two independent flush chains.
// Pad-edge trick: chunk registers init to (7<<17, 0) => et=7, y=0. Padded slots
// gather the L1-hot row 0 and add exactly 0; since edges are rel-sorted, an
// et=7 pad can only flush a completed segment and the final rel-7 store adds
// only zeros -> bitwise correct with no remainder loop and no clamped loads.
__launch_bounds__(256)
__global__ void k_fused(const unsigned short* __restrict__ xin,
                        const int* __restrict__ rowptr8, const int2* __restrict__ edata,
                        const unsigned short* __restrict__ WpF, const float* __restrict__ bias,
                        float* __restrict__ outf, unsigned short* __restrict__ outb, int mode) {
    __shared__ __align__(16) unsigned short agg[16 * 520];
    int t = threadIdx.x;
    int wave = t >> 6, lane = t & 63;
    int n0 = blockIdx.x * 16;
    // each wave zero-inits only its OWN 4 rows (rows wave*4 .. wave*4+3);
    // it is also the only wave that writes them during the edge phase, so no
    // barrier is needed before the edge loop.
    {
        int* a4 = (int*)agg + wave * 4 * 260;
        for (int i = lane; i < 4 * 260; i += 64) a4[i] = 0;
    }
    for (int np = 0; np < 2; np++) {
        int lrowA = wave * 4 + np * 2;
        int lrowB = lrowA + 1;
        int nodeA = n0 + lrowA, nodeB = n0 + lrowB;
        int a0 = rowptr8[(size_t)nodeA * 8];
        int a1 = rowptr8[(size_t)nodeA * 8 + 8];
        int b0 = rowptr8[(size_t)nodeB * 8];
        int b1 = rowptr8[(size_t)nodeB * 8 + 8];
        unsigned short* aggrowA = agg + lrowA * 520;
        unsigned short* aggrowB = agg + lrowB * 520;
        float accA = 0.f, accB = 0.f;
        int curA = 0, curB = 0;
        int jcA = a0, jcB = b0;
        while (jcA < a1 || jcB < b1) {
            int mA = a1 - jcA; mA = mA < 0 ? 0 : (mA > 64 ? 64 : mA);
            int mB = b1 - jcB; mB = mB < 0 ? 0 : (mB > 64 ? 64 : mB);
            int2 edA = make_int2(7 << 17, 0);
            int2 edB = make_int2(7 << 17, 0);
            if (lane < mA) edA = edata[jcA + lane];
            if (lane < mB) edB = edata[jcB + lane];
            int mm = mA > mB ? mA : mB;
#define RL1(S,k) int x##S##k = __builtin_amdgcn_readlane(ed##S.x, i + k); \
                 int y##S##k = __builtin_amdgcn_readlane(ed##S.y, i + k);
#define LD1(S,k) unsigned short v##S##k = xin[((size_t)(unsigned)(x##S##k & 0x1FFFF) << 6) + lane];
#define CO1(S,k) { int et = (x##S##k >> 17) & 7; \
                   if (et != cur##S) { aggrow##S[cur##S * 64 + lane] = f2bf(acc##S); acc##S = 0.f; cur##S = et; } \
                   acc##S = fmaf(__int_as_float(y##S##k), bf2f(v##S##k), acc##S); }
            for (int i = 0; i < mm; i += 8) {
                RL1(A,0) RL1(A,1) RL1(A,2) RL1(A,3) RL1(A,4) RL1(A,5) RL1(A,6) RL1(A,7)
                RL1(B,0) RL1(B,1) RL1(B,2) RL1(B,3) RL1(B,4) RL1(B,5) RL1(B,6) RL1(B,7)
                LD1(A,0) LD1(A,1) LD1(A,2) LD1(A,3) LD1(A,4) LD1(A,5) LD1(A,6) LD1(A,7)
                LD1(B,0) LD1(B,1) LD1(B,2) LD1(B,3) LD1(B,4) LD1(B,5) LD1(B,6) LD1(B,7)
                CO1(A,0) CO1(A,1) CO1(A,2) CO1(A,3) CO1(A,4) CO1(A,5) CO1(A,6) CO1(A,7)
                CO1(B,0) CO1(B,1) CO1(B,2) CO1(B,3) CO1(B,4) CO1(B,5) CO1(B,6) CO1(B,7)
            }
#undef RL1
#undef LD1
#undef CO1
            jcA += mA;
            jcB += mB;
        }
        aggrowA[curA * 64 + lane] = f2bf(accA);
        aggrowB[curB * 64 + lane] = f2bf(accB);
    }
    __syncthreads();
    // ---- MFMA: [16 nodes x 512] @ WpF -> 64 outs; wave covers cols [wave*16, +16)
    int q = lane >> 4, c = lane & 15;
    int o16 = wave * 16;
    f32x4 accd = (f32x4){0.f, 0.f, 0.f, 0.f};
    const bf16x8* B8 = (const bf16x8*)WpF;
#pragma unroll
    for (int s = 0; s < 16; s++) {
        bf16x8 a = *(const bf16x8*)&agg[c * 520 + s * 32 + q * 8];
        bf16x8 bfr = B8[(s * 4 + q) * 64 + o16 + c];
        accd = __builtin_amdgcn_mfma_f32_16x16x32_bf16(a, bfr, accd, 0, 0, 0);
    }
    int col = o16 + c;
    float bia = bias[col];
#pragma unroll
    for (int r = 0; r < 4; r++) {
        int node = n0 + q * 4 + r;
        float v = accd[r] + bia;
        if (mode == 1) {
            v = fmaxf(v, 0.f);
            outb[(size_t)node * 64 + col] = f2bf(v);
        } else {
            outf[(size_t)node * 64 + col] = v;
        }
    }
}

extern "C" void kernel_launch(void* const* d_in, const int* in_sizes, int n_in,
                              void* d_out, int out_size, void* d_ws, size_t ws_size,
                              hipStream_t stream) {
    const int*   feat  = (const int*)d_in[0];
    const int*   src   = (const int*)d_in[1];
    const int*   dst   = (const int*)d_in[2];
    const int*   etype = (const int*)d_in[3];
    const float* norm  = (const float*)d_in[4];
    const float* emb_w = (const float*)d_in[5];
    const float* sm_w  = (const float*)d_in[6];
    const float* sm_b  = (const float*)d_in[7];
    const float* V1    = (const float*)d_in[8];
    const float* comp1 = (const float*)d_in[9];
    const float* b1    = (const float*)d_in[10];
    const float* V2    = (const float*)d_in[11];
    const float* comp2 = (const float*)d_in[12];
    const float* b2    = (const float*)d_in[13];
    float* out = (float*)d_out;

    char* p = (char*)d_ws;
    auto alloc = [&](size_t bytes) { void* q = (void*)p; p += (bytes + 255) & ~(size_t)255; return q; };
    unsigned short* xb   = (unsigned short*)alloc((size_t)N_PAD * 64 * 2);  // 12.8 MB
    unsigned short* hb   = (unsigned short*)alloc((size_t)N_PAD * 64 * 2);  // 12.8 MB
    unsigned short* WpF1 = (unsigned short*)alloc((size_t)KF * HD * 2);     // 64 KB
    unsigned short* WpF2 = (unsigned short*)alloc((size_t)KF * HD * 2);
    unsigned short* smPack = (unsigned short*)alloc(KDIM * HD * 2);         // 32 KB
    int*   cnt    = (int*)alloc((size_t)NBLK_P * NBUCK * 4);                // 803 KB
    int*   boffm  = (int*)alloc((size_t)NBLK_P * NBUCK * 4);                // 803 KB
    int*   btot   = (int*)alloc((size_t)NBUCK * 4);
    int*   bstart = (int*)alloc((size_t)(NBUCK + 1) * 4);
    int*   rowptr8 = (int*)alloc(((size_t)N_NODES * 8 + 1) * 4);            // 3.2 MB
    int2*  staged = (int2*)alloc((size_t)N_EDGES * 8);                      // 12.8 MB
    int2*  edata  = (int2*)alloc((size_t)N_EDGES * 8);                      // 12.8 MB

    k_weights<<<320, 256, 0, stream>>>(V1, comp1, V2, comp2, sm_w, WpF1, WpF2, smPack);

    k_pcount<<<NBLK_P, TPB_P, 0, stream>>>(dst, cnt);
    k_pscan<<<NBUCK_USED, NBLK_P, 0, stream>>>(cnt, boffm, btot);
    k_bscan<<<1, 512, 0, stream>>>(btot, bstart, rowptr8);
    k_pscatter<<<NBLK_P, TPB_P, 0, stream>>>(src, dst, etype, norm, boffm, bstart, staged);
    k_finalize<<<NBUCK_USED, 512, 0, stream>>>(staged, bstart, btot, rowptr8, edata);

    k_sizematch<<<N_PAD / 64, 256, 0, stream>>>(feat, emb_w, smPack, sm_b, xb);

    k_fused<<<N_NODES / 16, 256, 0, stream>>>(xb, rowptr8, edata, WpF1, b1, nullptr, hb, 1);
    k_fused<<<N_NODES / 16, 256, 0, stream>>>(hb, rowptr8, edata, WpF2, b2, out, nullptr, 0);
}

// Round 4
// 304.291 us; speedup vs baseline: 4.9791x; 1.0181x over previous
//
#include <hip/hip_runtime.h>

#define N_NODES 100000
#define N_PAD 100032      // padded to 64-node tiles for MFMA sizematch
#define N_EDGES 1600000
#define NUM_RELS 8
#define KDIM 256      // E_DIM * MAX_LEN
#define HD 64
#define KF 512        // fused GEMM K = NUM_RELS * 64

// CSR-build partition parameters: 256-node coarse buckets
#define B_SHIFT 8
#define NBUCK 392         // ceil(100000/256)=391, +1 pad
#define NBUCK_USED 391
#define NBLK_P 512
#define TPB_P 256
#define EPB 3125          // 512 * 3125 = 1.6M exactly

typedef __attribute__((ext_vector_type(8))) short bf16x8;
typedef __attribute__((ext_vector_type(4))) float f32x4;

// plain-POD edge pair for constant-addrspace scalar loads
struct EP { int x, y; };
typedef const __attribute__((address_space(4))) EP*  ep_cptr;
typedef const __attribute__((address_space(4))) int* ci_cptr;

__device__ inline unsigned short f2bf(float f) {
    unsigned u = __float_as_uint(f);
    u += 0x7fff + ((u >> 16) & 1);   // round-to-nearest-even
    return (unsigned short)(u >> 16);
}
__device__ inline float bf2f(unsigned short s) {
    return __uint_as_float(((unsigned)s) << 16);
}
__device__ inline unsigned packtrunc(float x, float y) {
    return (__float_as_uint(x) >> 16) | (__float_as_uint(y) & 0xffff0000u);
}

// ---------------- weights:
//  WpF_l: B-fragment layout over K=512: WpF[((s*4+q)*64+o)*8+j] = Wfull[kk=s*32+q*8+j][o]
//  where Wfull[r*64+k][o] = sum_b comp[r,b] V[b,k,o]
//  smPack: B-fragment layout for size matcher (K=256)
__global__ void k_weights(const float* __restrict__ V1, const float* __restrict__ comp1,
                          const float* __restrict__ V2, const float* __restrict__ comp2,
                          const float* __restrict__ sm_w,
                          unsigned short* __restrict__ WpF1, unsigned short* __restrict__ WpF2,
                          unsigned short* __restrict__ smPack) {
    int idx = blockIdx.x * 256 + threadIdx.x;
    if (idx < 2 * NUM_RELS * 64 * 64) {
        int l = idx >> 15;
        int r = (idx >> 12) & 7;
        int k = (idx >> 6) & 63;
        int o = idx & 63;
        const float* V = l ? V2 : V1;
        const float* comp = l ? comp2 : comp1;
        float s = 0.f;
#pragma unroll
        for (int b = 0; b < 8; b++) s += comp[r * 8 + b] * V[(b * 64 + k) * 64 + o];
        int kk = r * 64 + k;
        int ss = kk >> 5, q = (kk >> 3) & 3, j = kk & 7;
        unsigned short* Wp = l ? WpF2 : WpF1;
        Wp[(((ss * 4 + q) * 64) + o) * 8 + j] = f2bf(s);
    } else {
        int j = idx - 65536;
        if (j < KDIM * HD) {
            int k = j >> 6, o = j & 63;
            int s = k >> 5, q = (k >> 3) & 3, jj = k & 7;
            smPack[(((s * 4 + q) * 64) + o) * 8 + jj] = f2bf(sm_w[o * KDIM + k]);
        }
    }
}

// ---------------- pass A: per-block LDS histogram over coarse buckets
__launch_bounds__(TPB_P)
__global__ void k_pcount(const int* __restrict__ dst, int* __restrict__ cnt) {
    __shared__ int lh[NBUCK];
    int t = threadIdx.x, blk = blockIdx.x;
    for (int b = t; b < NBUCK; b += TPB_P) lh[b] = 0;
    __syncthreads();
    int base = blk * EPB;
    for (int i = t; i < EPB; i += TPB_P) atomicAdd(&lh[dst[base + i] >> B_SHIFT], 1);
    __syncthreads();
    for (int b = t; b < NBUCK; b += TPB_P) cnt[blk * NBUCK + b] = lh[b];
}

// ---------------- pass B1: per-bucket exclusive scan across the NBLK_P blocks
__launch_bounds__(NBLK_P)
__global__ void k_pscan(const int* __restrict__ cnt, int* __restrict__ boffm, int* __restrict__ btot) {
    __shared__ int s[NBLK_P];
    int b = blockIdx.x, t = threadIdx.x;
    int v = cnt[t * NBUCK + b];
    s[t] = v;
    __syncthreads();
    for (int off = 1; off < NBLK_P; off <<= 1) {
        int u = (t >= off) ? s[t - off] : 0;
        __syncthreads();
        s[t] += u;
        __syncthreads();
    }
    boffm[t * NBUCK + b] = s[t] - v;
    if (t == NBLK_P - 1) btot[b] = s[NBLK_P - 1];
}

// ---------------- pass B2: exclusive scan over bucket totals -> bucket starts; sentinel
__launch_bounds__(512)
__global__ void k_bscan(const int* __restrict__ btot, int* __restrict__ bstart, int* __restrict__ rowptr8) {
    __shared__ int s[512];
    int t = threadIdx.x;
    int v = (t < NBUCK_USED) ? btot[t] : 0;
    s[t] = v;
    __syncthreads();
    for (int off = 1; off < 512; off <<= 1) {
        int u = (t >= off) ? s[t - off] : 0;
        __syncthreads();
        s[t] += u;
        __syncthreads();
    }
    bstart[t] = s[t] - v;
    if (t == 0) rowptr8[(size_t)N_NODES * 8] = N_EDGES;
}

// ---------------- pass C: scatter edges into bucket-contiguous staging
// packed = src | et<<17 | dlocal<<20  -> key = (packed>>17)&2047 = dlocal*8+et
__launch_bounds__(TPB_P)
__global__ void k_pscatter(const int* __restrict__ src, const int* __restrict__ dst,
                           const int* __restrict__ et, const float* __restrict__ norm,
                           const int* __restrict__ boffm, const int* __restrict__ bstart,
                           int2* __restrict__ staged) {
    __shared__ int ldsoff[NBUCK];
    int t = threadIdx.x, blk = blockIdx.x;
    for (int b = t; b < NBUCK; b += TPB_P) ldsoff[b] = bstart[b] + boffm[blk * NBUCK + b];
    __syncthreads();
    int base = blk * EPB;
    for (int i = t; i < EPB; i += TPB_P) {
        int e = base + i;
        int d = dst[e];
        int bu = d >> B_SHIFT;
        int pos = atomicAdd(&ldsoff[bu], 1);
        int packed = src[e] | (et[e] << 17) | ((d & 255) << 20);
        staged[pos] = make_int2(packed, __float_as_int(norm[e]));
    }
}

// ---------------- pass D: per-bucket 2048-bin counting sort -> rowptr8 + sorted edata
// edata stores x = (src<<7) | et  (byte offset of xin row in bits 7..23, rel in 0..2)
__launch_bounds__(512)
__global__ void k_finalize(const int2* __restrict__ staged, const int* __restrict__ bstart,
                           const int* __restrict__ btot, int* __restrict__ rowptr8,
                           int2* __restrict__ edata) {
    __shared__ int lh[2048];
    __shared__ int s512[512];
    __shared__ int lsc[2048];
    int b = blockIdx.x, t = threadIdx.x;
    int base = bstart[b];
    int cnt = btot[b];
    lh[t] = 0; lh[t + 512] = 0; lh[t + 1024] = 0; lh[t + 1536] = 0;
    __syncthreads();
    int2 held[9];
    int key[9], rank[9];
    int nh = 0;
    for (int i = t; i < cnt; i += 512) {
        int2 ed = staged[base + i];
        int k = (ed.x >> 17) & 2047;
        held[nh] = ed; key[nh] = k; rank[nh] = atomicAdd(&lh[k], 1); nh++;
    }
    __syncthreads();
    int b0 = lh[t * 4], b1 = lh[t * 4 + 1], b2 = lh[t * 4 + 2], b3 = lh[t * 4 + 3];
    int tot = b0 + b1 + b2 + b3;
    s512[t] = tot;
    __syncthreads();
    for (int off = 1; off < 512; off <<= 1) {
        int u = (t >= off) ? s512[t - off] : 0;
        __syncthreads();
        s512[t] += u;
        __syncthreads();
    }
    int excl = s512[t] - tot;
    lsc[t * 4] = excl;
    lsc[t * 4 + 1] = excl + b0;
    lsc[t * 4 + 2] = excl + b0 + b1;
    lsc[t * 4 + 3] = excl + b0 + b1 + b2;
    __syncthreads();
    int limit = (N_NODES << 3) - (b << 11);
    for (int idx = t; idx < 2048; idx += 512)
        if (idx < limit) rowptr8[(b << 11) + idx] = base + lsc[idx];
    for (int i = 0; i < nh; i++) {
        int p = base + lsc[key[i]] + rank[i];
        int srcv = held[i].x & 0x1FFFF;
        int etv  = (held[i].x >> 17) & 7;
        edata[p] = make_int2((srcv << 7) | etv, held[i].y);   // byte-offset | et
    }
}

// ---------------- size matcher (MFMA, no LDS)
__launch_bounds__(256)
__global__ void k_sizematch(const int* __restrict__ feat, const float* __restrict__ emb_w,
                            const unsigned short* __restrict__ smPack, const float* __restrict__ sm_b,
                            unsigned short* __restrict__ xb) {
    int t = threadIdx.x;
    int wave = t >> 6, lane = t & 63;
    int q = lane >> 4, c = lane & 15;
    int n0 = blockIdx.x * 64 + wave * 16;
    int node = n0 + c;
    int nclamp = (node < N_NODES) ? node : (N_NODES - 1);
    const int4* fr = (const int4*)(feat + (size_t)nclamp * 8);
    int4 f0 = fr[0], f1 = fr[1];
    int fidx[8] = {f0.x, f0.y, f0.z, f0.w, f1.x, f1.y, f1.z, f1.w};
    f32x4 acc[4];
#pragma unroll
    for (int i = 0; i < 4; i++) acc[i] = (f32x4){0.f, 0.f, 0.f, 0.f};
    const bf16x8* B8 = (const bf16x8*)smPack;
#pragma unroll
    for (int s = 0; s < 8; s++) {
        const float4* ar = (const float4*)(emb_w + (size_t)fidx[s] * 32 + q * 8);
        float4 a0 = ar[0], a1 = ar[1];
        union { unsigned u[4]; bf16x8 v; } A;
        A.u[0] = packtrunc(a0.x, a0.y);
        A.u[1] = packtrunc(a0.z, a0.w);
        A.u[2] = packtrunc(a1.x, a1.y);
        A.u[3] = packtrunc(a1.z, a1.w);
#pragma unroll
        for (int tl = 0; tl < 4; tl++) {
            bf16x8 b = B8[(s * 4 + q) * 64 + tl * 16 + c];
            acc[tl] = __builtin_amdgcn_mfma_f32_16x16x32_bf16(A.v, b, acc[tl], 0, 0, 0);
        }
    }
    int row_base = n0 + q * 4;
    bool full = (n0 + 15 < N_NODES);
#pragma unroll
    for (int tl = 0; tl < 4; tl++) {
        int o = tl * 16 + c;
        float bia = sm_b[o];
#pragma unroll
        for (int r = 0; r < 4; r++) {
            int nd = row_base + r;
            if (full || nd < N_NODES)
                xb[(size_t)nd * 64 + o] = f2bf(acc[tl][r] + bia);
        }
    }
}

// ---------------- fused layer: scalar-load dual-stream aggregation + MFMA
// block: 256 thr = 4 waves; 16 nodes/block (4 per wave); grid N_NODES/16.
// Edge descriptors are loaded through addrspace(4) (constant) at uniform,
// readfirstlane-seeded indices -> compiler emits s_load into SGPRs. No
// per-edge readlanes, no vector chunk loads, no exec masking. Gathers use
// scalar base (byte offset pre-packed in edata.x bits 7..23) + lane offset.
// Tail: one clamp-masked 8-group per stream (y forced 0, flush guarded).
__launch_bounds__(256)
__global__ void k_fused(const unsigned short* __restrict__ xin,
                        const int* __restrict__ rowptr8, const int2* __restrict__ edata,
                        const unsigned short* __restrict__ WpF, const float* __restrict__ bias,
                        float* __restrict__ outf, unsigned short* __restrict__ outb, int mode) {
    __shared__ __align__(16) unsigned short agg[16 * 520];
    int t = threadIdx.x;
    int wave = t >> 6, lane = t & 63;
    int n0 = blockIdx.x * 16;
    ep_cptr ep4 = (ep_cptr)(unsigned long long)edata;
    ci_cptr rp4 = (ci_cptr)(unsigned long long)rowptr8;
    // each wave zero-inits only its OWN 4 rows; it is also the only writer of
    // them during the edge phase, so no barrier is needed before the edge loop.
    {
        int* a4 = (int*)agg + wave * 4 * 260;
        for (int i = lane; i < 4 * 260; i += 64) a4[i] = 0;
    }
#define EF(S,k)  int x##S##k = ep4[j##S + (k)].x, y##S##k = ep4[j##S + (k)].y;
#define EFM(S,k) int q##S##k = j##S + (k); \
                 int c##S##k = (q##S##k <= last##S) ? q##S##k : last##S; \
                 c##S##k = (c##S##k < 0) ? 0 : c##S##k; \
                 int x##S##k = ep4[c##S##k].x; \
                 int y##S##k = (q##S##k <= last##S) ? ep4[c##S##k].y : 0; \
                 int vd##S##k = (q##S##k <= last##S);
#define GF(S,k)  unsigned short w##S##k = *((const unsigned short*)((const char*)xin + (x##S##k & 0x00FFFF80)) + lane);
#define CN(S,k)  { int et = x##S##k & 7; \
                   if (et != cur##S) { aggrow##S[cur##S * 64 + lane] = f2bf(acc##S); acc##S = 0.f; cur##S = et; } \
                   acc##S = fmaf(__int_as_float(y##S##k), bf2f(w##S##k), acc##S); }
#define CNM(S,k) { int et = x##S##k & 7; \
                   if (vd##S##k && et != cur##S) { aggrow##S[cur##S * 64 + lane] = f2bf(acc##S); acc##S = 0.f; cur##S = et; } \
                   acc##S = fmaf(__int_as_float(y##S##k), bf2f(w##S##k), acc##S); }
#define EF8(S)   EF(S,0) EF(S,1) EF(S,2) EF(S,3) EF(S,4) EF(S,5) EF(S,6) EF(S,7)
#define EFM8(S)  EFM(S,0) EFM(S,1) EFM(S,2) EFM(S,3) EFM(S,4) EFM(S,5) EFM(S,6) EFM(S,7)
#define GF8(S)   GF(S,0) GF(S,1) GF(S,2) GF(S,3) GF(S,4) GF(S,5) GF(S,6) GF(S,7)
#define CN8(S)   CN(S,0) CN(S,1) CN(S,2) CN(S,3) CN(S,4) CN(S,5) CN(S,6) CN(S,7)
#define CNM8(S)  CNM(S,0) CNM(S,1) CNM(S,2) CNM(S,3) CNM(S,4) CNM(S,5) CNM(S,6) CNM(S,7)
    for (int np = 0; np < 2; np++) {
        int lrowA = wave * 4 + np * 2;
        int lrowB = lrowA + 1;
        int nA = __builtin_amdgcn_readfirstlane(n0 + lrowA);
        int nB = nA + 1;
        int j0A = rp4[(size_t)nA * 8], j1A = rp4[(size_t)nA * 8 + 8];
        int j0B = rp4[(size_t)nB * 8], j1B = rp4[(size_t)nB * 8 + 8];
        unsigned short* aggrowA = agg + lrowA * 520;
        unsigned short* aggrowB = agg + lrowB * 520;
        float accA = 0.f, accB = 0.f;
        int curA = 0, curB = 0;
        int jA = j0A, jB = j0B;
        while (jA + 8 <= j1A && jB + 8 <= j1B) {
            EF8(A) EF8(B) GF8(A) GF8(B) CN8(A) CN8(B)
            jA += 8; jB += 8;
        }
        while (jA + 8 <= j1A) { EF8(A) GF8(A) CN8(A) jA += 8; }
        while (jB + 8 <= j1B) { EF8(B) GF8(B) CN8(B) jB += 8; }
        {
            int lastA = j1A - 1, lastB = j1B - 1;
            if (((j1A - jA) | (j1B - jB)) > 0) {
                EFM8(A) EFM8(B) GF8(A) GF8(B) CNM8(A) CNM8(B)
            }
        }
        aggrowA[curA * 64 + lane] = f2bf(accA);
        aggrowB[curB * 64 + lane] = f2bf(accB);
    }
#undef EF
#undef EFM
#undef GF
#undef CN
#undef CNM
#undef EF8
#undef EFM8
#undef GF8
#undef CN8
#undef CNM8
    __syncthreads();
    // ---- MFMA: [16 nodes x 512] @ WpF -> 64 outs; wave covers cols [wave*16, +16)
    int q = lane >> 4, c = lane & 15;
    int o16 = wave * 16;
    f32x4 accd = (f32x4){0.f, 0.f, 0.f, 0.f};
    const bf16x8* B8 = (const bf16x8*)WpF;
#pragma unroll
    for (int s = 0; s < 16; s++) {
        bf16x8 a = *(const bf16x8*)&agg[c * 520 + s * 32 + q * 8];
        bf16x8 bfr = B8[(s * 4 + q) * 64 + o16 + c];
        accd = __builtin_amdgcn_mfma_f32_16x16x32_bf16(a, bfr, accd, 0, 0, 0);
    }
    int col = o16 + c;
    float bia = bias[col];
#pragma unroll
    for (int r = 0; r < 4; r++) {
        int node = n0 + q * 4 + r;
        float v = accd[r] + bia;
        if (mode == 1) {
            v = fmaxf(v, 0.f);
            outb[(size_t)node * 64 + col] = f2bf(v);
        } else {
            outf[(size_t)node * 64 + col] = v;
        }
    }
}

extern "C" void kernel_launch(void* const* d_in, const int* in_sizes, int n_in,
                              void* d_out, int out_size, void* d_ws, size_t ws_size,
                              hipStream_t stream) {
    const int*   feat  = (const int*)d_in[0];
    const int*   src   = (const int*)d_in[1];
    const int*   dst   = (const int*)d_in[2];
    const int*   etype = (const int*)d_in[3];
    const float* norm  = (const float*)d_in[4];
    const float* emb_w = (const float*)d_in[5];
    const float* sm_w  = (const float*)d_in[6];
    const float* sm_b  = (const float*)d_in[7];
    const float* V1    = (const float*)d_in[8];
    const float* comp1 = (const float*)d_in[9];
    const float* b1    = (const float*)d_in[10];
    const float* V2    = (const float*)d_in[11];
    const float* comp2 = (const float*)d_in[12];
    const float* b2    = (const float*)d_in[13];
    float* out = (float*)d_out;

    char* p = (char*)d_ws;
    auto alloc = [&](size_t bytes) { void* q = (void*)p; p += (bytes + 255) & ~(size_t)255; return q; };
    unsigned short* xb   = (unsigned short*)alloc((size_t)N_PAD * 64 * 2);  // 12.8 MB
    unsigned short* hb   = (unsigned short*)alloc((size_t)N_PAD * 64 * 2);  // 12.8 MB
    unsigned short* WpF1 = (unsigned short*)alloc((size_t)KF * HD * 2);     // 64 KB
    unsigned short* WpF2 = (unsigned short*)alloc((size_t)KF * HD * 2);
    unsigned short* smPack = (unsigned short*)alloc(KDIM * HD * 2);         // 32 KB
    int*   cnt    = (int*)alloc((size_t)NBLK_P * NBUCK * 4);                // 803 KB
    int*   boffm  = (int*)alloc((size_t)NBLK_P * NBUCK * 4);                // 803 KB
    int*   btot   = (int*)alloc((size_t)NBUCK * 4);
    int*   bstart = (int*)alloc((size_t)(NBUCK + 1) * 4);
    int*   rowptr8 = (int*)alloc(((size_t)N_NODES * 8 + 1) * 4);            // 3.2 MB
    int2*  staged = (int2*)alloc((size_t)N_EDGES * 8);                      // 12.8 MB
    int2*  edata  = (int2*)alloc((size_t)N_EDGES * 8);                      // 12.8 MB

    k_weights<<<320, 256, 0, stream>>>(V1, comp1, V2, comp2, sm_w, WpF1, WpF2, smPack);

    k_pcount<<<NBLK_P, TPB_P, 0, stream>>>(dst, cnt);
    k_pscan<<<NBUCK_USED, NBLK_P, 0, stream>>>(cnt, boffm, btot);
    k_bscan<<<1, 512, 0, stream>>>(btot, bstart, rowptr8);
    k_pscatter<<<NBLK_P, TPB_P, 0, stream>>>(src, dst, etype, norm, boffm, bstart, staged);
    k_finalize<<<NBUCK_USED, 512, 0, stream>>>(staged, bstart, btot, rowptr8, edata);

    k_sizematch<<<N_PAD / 64, 256, 0, stream>>>(feat, emb_w, smPack, sm_b, xb);

    k_fused<<<N_NODES / 16, 256, 0, stream>>>(xb, rowptr8, edata, WpF1, b1, nullptr, hb, 1);
    k_fused<<<N_NODES / 16, 256, 0, stream>>>(hb, rowptr8, edata, WpF2, b2, out, nullptr, 0);
}

// Round 5
// 299.805 us; speedup vs baseline: 5.0536x; 1.0150x over previous
//
#include <hip/hip_runtime.h>

#define N_NODES 100000
#define N_PAD 100032      // padded to 64-node tiles for MFMA sizematch
#define N_EDGES 1600000
#define NUM_RELS 8
#define KDIM 256      // E_DIM * MAX_LEN
#define HD 64
#define KF 512        // fused GEMM K = NUM_RELS * 64

// CSR-build partition parameters: 256-node coarse buckets
#define B_SHIFT 8
#define NBUCK 392         // ceil(100000/256)=391, +1 pad
#define NBUCK_USED 391
#define NBLK_P 512
#define TPB_P 256
#define EPB 3125          // 512 * 3125 = 1.6M exactly

typedef __attribute__((ext_vector_type(8))) short bf16x8;
typedef __attribute__((ext_vector_type(4))) float f32x4;

// plain-POD edge pair for constant-addrspace scalar loads
struct EP { int x, y; };
typedef const __attribute__((address_space(4))) EP*  ep_cptr;
typedef const __attribute__((address_space(4))) int* ci_cptr;

__device__ inline unsigned short f2bf(float f) {
    unsigned u = __float_as_uint(f);
    u += 0x7fff + ((u >> 16) & 1);   // round-to-nearest-even
    return (unsigned short)(u >> 16);
}
__device__ inline float bf2f(unsigned short s) {
    return __uint_as_float(((unsigned)s) << 16);
}
__device__ inline unsigned packtrunc(float x, float y) {
    return (__float_as_uint(x) >> 16) | (__float_as_uint(y) & 0xffff0000u);
}

// ---------------- weights:
//  WpF_l: B-fragment layout over K=512: WpF[((s*4+q)*64+o)*8+j] = Wfull[kk=s*32+q*8+j][o]
//  where Wfull[r*64+k][o] = sum_b comp[r,b] V[b,k,o]
//  smPack: B-fragment layout for size matcher (K=256)
__global__ void k_weights(const float* __restrict__ V1, const float* __restrict__ comp1,
                          const float* __restrict__ V2, const float* __restrict__ comp2,
                          const float* __restrict__ sm_w,
                          unsigned short* __restrict__ WpF1, unsigned short* __restrict__ WpF2,
                          unsigned short* __restrict__ smPack) {
    int idx = blockIdx.x * 256 + threadIdx.x;
    if (idx < 2 * NUM_RELS * 64 * 64) {
        int l = idx >> 15;
        int r = (idx >> 12) & 7;
        int k = (idx >> 6) & 63;
        int o = idx & 63;
        const float* V = l ? V2 : V1;
        const float* comp = l ? comp2 : comp1;
        float s = 0.f;
#pragma unroll
        for (int b = 0; b < 8; b++) s += comp[r * 8 + b] * V[(b * 64 + k) * 64 + o];
        int kk = r * 64 + k;
        int ss = kk >> 5, q = (kk >> 3) & 3, j = kk & 7;
        unsigned short* Wp = l ? WpF2 : WpF1;
        Wp[(((ss * 4 + q) * 64) + o) * 8 + j] = f2bf(s);
    } else {
        int j = idx - 65536;
        if (j < KDIM * HD) {
            int k = j >> 6, o = j & 63;
            int s = k >> 5, q = (k >> 3) & 3, jj = k & 7;
            smPack[(((s * 4 + q) * 64) + o) * 8 + jj] = f2bf(sm_w[o * KDIM + k]);
        }
    }
}

// ---------------- pass A: per-block LDS histogram over coarse buckets
__launch_bounds__(TPB_P)
__global__ void k_pcount(const int* __restrict__ dst, int* __restrict__ cnt) {
    __shared__ int lh[NBUCK];
    int t = threadIdx.x, blk = blockIdx.x;
    for (int b = t; b < NBUCK; b += TPB_P) lh[b] = 0;
    __syncthreads();
    int base = blk * EPB;
    for (int i = t; i < EPB; i += TPB_P) atomicAdd(&lh[dst[base + i] >> B_SHIFT], 1);
    __syncthreads();
    for (int b = t; b < NBUCK; b += TPB_P) cnt[blk * NBUCK + b] = lh[b];
}

// ---------------- pass B1: per-bucket exclusive scan across the NBLK_P blocks
__launch_bounds__(NBLK_P)
__global__ void k_pscan(const int* __restrict__ cnt, int* __restrict__ boffm, int* __restrict__ btot) {
    __shared__ int s[NBLK_P];
    int b = blockIdx.x, t = threadIdx.x;
    int v = cnt[t * NBUCK + b];
    s[t] = v;
    __syncthreads();
    for (int off = 1; off < NBLK_P; off <<= 1) {
        int u = (t >= off) ? s[t - off] : 0;
        __syncthreads();
        s[t] += u;
        __syncthreads();
    }
    boffm[t * NBUCK + b] = s[t] - v;
    if (t == NBLK_P - 1) btot[b] = s[NBLK_P - 1];
}

// ---------------- pass B2: exclusive scan over bucket totals -> bucket starts; sentinel
__launch_bounds__(512)
__global__ void k_bscan(const int* __restrict__ btot, int* __restrict__ bstart, int* __restrict__ rowptr8) {
    __shared__ int s[512];
    int t = threadIdx.x;
    int v = (t < NBUCK_USED) ? btot[t] : 0;
    s[t] = v;
    __syncthreads();
    for (int off = 1; off < 512; off <<= 1) {
        int u = (t >= off) ? s[t - off] : 0;
        __syncthreads();
        s[t] += u;
        __syncthreads();
    }
    bstart[t] = s[t] - v;
    if (t == 0) rowptr8[(size_t)N_NODES * 8] = N_EDGES;
}

// ---------------- pass C: scatter edges into bucket-contiguous staging
// packed = src | et<<17 | dlocal<<20  -> key = (packed>>17)&2047 = dlocal*8+et
__launch_bounds__(TPB_P)
__global__ void k_pscatter(const int* __restrict__ src, const int* __restrict__ dst,
                           const int* __restrict__ et, const float* __restrict__ norm,
                           const int* __restrict__ boffm, const int* __restrict__ bstart,
                           int2* __restrict__ staged) {
    __shared__ int ldsoff[NBUCK];
    int t = threadIdx.x, blk = blockIdx.x;
    for (int b = t; b < NBUCK; b += TPB_P) ldsoff[b] = bstart[b] + boffm[blk * NBUCK + b];
    __syncthreads();
    int base = blk * EPB;
    for (int i = t; i < EPB; i += TPB_P) {
        int e = base + i;
        int d = dst[e];
        int bu = d >> B_SHIFT;
        int pos = atomicAdd(&ldsoff[bu], 1);
        int packed = src[e] | (et[e] << 17) | ((d & 255) << 20);
        staged[pos] = make_int2(packed, __float_as_int(norm[e]));
    }
}

// ---------------- pass D: per-bucket 2048-bin counting sort -> rowptr8 + sorted edata
// edata stores x = (src<<7) | et  (byte offset of xin row in bits 7..23, rel in 0..2)
__launch_bounds__(512)
__global__ void k_finalize(const int2* __restrict__ staged, const int* __restrict__ bstart,
                           const int* __restrict__ btot, int* __restrict__ rowptr8,
                           int2* __restrict__ edata) {
    __shared__ int lh[2048];
    __shared__ int s512[512];
    __shared__ int lsc[2048];
    int b = blockIdx.x, t = threadIdx.x;
    int base = bstart[b];
    int cnt = btot[b];
    lh[t] = 0; lh[t + 512] = 0; lh[t + 1024] = 0; lh[t + 1536] = 0;
    __syncthreads();
    int2 held[9];
    int key[9], rank[9];
    int nh = 0;
    for (int i = t; i < cnt; i += 512) {
        int2 ed = staged[base + i];
        int k = (ed.x >> 17) & 2047;
        held[nh] = ed; key[nh] = k; rank[nh] = atomicAdd(&lh[k], 1); nh++;
    }
    __syncthreads();
    int b0 = lh[t * 4], b1 = lh[t * 4 + 1], b2 = lh[t * 4 + 2], b3 = lh[t * 4 + 3];
    int tot = b0 + b1 + b2 + b3;
    s512[t] = tot;
    __syncthreads();
    for (int off = 1; off < 512; off <<= 1) {
        int u = (t >= off) ? s512[t - off] : 0;
        __syncthreads();
        s512[t] += u;
        __syncthreads();
    }
    int excl = s512[t] - tot;
    lsc[t * 4] = excl;
    lsc[t * 4 + 1] = excl + b0;
    lsc[t * 4 + 2] = excl + b0 + b1;
    lsc[t * 4 + 3] = excl + b0 + b1 + b2;
    __syncthreads();
    int limit = (N_NODES << 3) - (b << 11);
    for (int idx = t; idx < 2048; idx += 512)
        if (idx < limit) rowptr8[(b << 11) + idx] = base + lsc[idx];
    for (int i = 0; i < nh; i++) {
        int p = base + lsc[key[i]] + rank[i];
        int srcv = held[i].x & 0x1FFFF;
        int etv  = (held[i].x >> 17) & 7;
        edata[p] = make_int2((srcv << 7) | etv, held[i].y);   // byte-offset | et
    }
}

// ---------------- size matcher (MFMA, no LDS)
__launch_bounds__(256)
__global__ void k_sizematch(const int* __restrict__ feat, const float* __restrict__ emb_w,
                            const unsigned short* __restrict__ smPack, const float* __restrict__ sm_b,
                            unsigned short* __restrict__ xb) {
    int t = threadIdx.x;
    int wave = t >> 6, lane = t & 63;
    int q = lane >> 4, c = lane & 15;
    int n0 = blockIdx.x * 64 + wave * 16;
    int node = n0 + c;
    int nclamp = (node < N_NODES) ? node : (N_NODES - 1);
    const int4* fr = (const int4*)(feat + (size_t)nclamp * 8);
    int4 f0 = fr[0], f1 = fr[1];
    int fidx[8] = {f0.x, f0.y, f0.z, f0.w, f1.x, f1.y, f1.z, f1.w};
    f32x4 acc[4];
#pragma unroll
    for (int i = 0; i < 4; i++) acc[i] = (f32x4){0.f, 0.f, 0.f, 0.f};
    const bf16x8* B8 = (const bf16x8*)smPack;
#pragma unroll
    for (int s = 0; s < 8; s++) {
        const float4* ar = (const float4*)(emb_w + (size_t)fidx[s] * 32 + q * 8);
        float4 a0 = ar[0], a1 = ar[1];
        union { unsigned u[4]; bf16x8 v; } A;
        A.u[0] = packtrunc(a0.x, a0.y);
        A.u[1] = packtrunc(a0.z, a0.w);
        A.u[2] = packtrunc(a1.x, a1.y);
        A.u[3] = packtrunc(a1.z, a1.w);
#pragma unroll
        for (int tl = 0; tl < 4; tl++) {
            bf16x8 b = B8[(s * 4 + q) * 64 + tl * 16 + c];
            acc[tl] = __builtin_amdgcn_mfma_f32_16x16x32_bf16(A.v, b, acc[tl], 0, 0, 0);
        }
    }
    int row_base = n0 + q * 4;
    bool full = (n0 + 15 < N_NODES);
#pragma unroll
    for (int tl = 0; tl < 4; tl++) {
        int o = tl * 16 + c;
        float bia = sm_b[o];
#pragma unroll
        for (int r = 0; r < 4; r++) {
            int nd = row_base + r;
            if (full || nd < N_NODES)
                xb[(size_t)nd * 64 + o] = f2bf(acc[tl][r] + bia);
        }
    }
}

// ---------------- fused layer: branchless always-write aggregation + MFMA
// block: 256 thr = 4 waves; 16 nodes/block (4 per wave); grid N_NODES/16.
// Edge descriptors via addrspace(4) scalar loads (s_load into SGPRs).
// Consume is BRANCHLESS: keep = (et==prev), acc = fma(y,w, acc*keep), and the
// running sum is stored to agg[row][et*64+lane] EVERY edge (shift-16 store ->
// ds_write_b16_d16_hi, half-up rounding). The last write of each rel segment
// leaves the final value; no flush state machine, no data-dependent branches.
// Tail: clamp slot index to the last valid edge (same et as prev -> keep=1,
// y=0 -> rewrites the same value; deg-0 rows write 0 over zero-init). 
__launch_bounds__(256)
__global__ void k_fused(const unsigned short* __restrict__ xin,
                        const int* __restrict__ rowptr8, const int2* __restrict__ edata,
                        const unsigned short* __restrict__ WpF, const float* __restrict__ bias,
                        float* __restrict__ outf, unsigned short* __restrict__ outb, int mode) {
    __shared__ __align__(16) unsigned short agg[16 * 520];
    int t = threadIdx.x;
    int wave = t >> 6, lane = t & 63;
    int n0 = blockIdx.x * 16;
    ep_cptr ep4 = (ep_cptr)(unsigned long long)edata;
    ci_cptr rp4 = (ci_cptr)(unsigned long long)rowptr8;
    // each wave zero-inits only its OWN 4 rows; it is also the only writer of
    // them during the edge phase, so no barrier is needed before the edge loop.
    {
        int* a4 = (int*)agg + wave * 4 * 260;
        for (int i = lane; i < 4 * 260; i += 64) a4[i] = 0;
    }
#define EF(S,k)  int x##S##k = ep4[j##S + (k)].x, y##S##k = ep4[j##S + (k)].y;
#define EFM(S,k) int q##S##k = j##S + (k); \
                 int c##S##k = (q##S##k <= last##S) ? q##S##k : last##S; \
                 c##S##k = (c##S##k < 0) ? 0 : c##S##k; \
                 int x##S##k = ep4[c##S##k].x; \
                 int y##S##k = (q##S##k <= last##S) ? ep4[c##S##k].y : 0;
#define GF(S,k)  unsigned short w##S##k = *((const unsigned short*)((const char*)xin + (x##S##k & 0x00FFFF80)) + lane);
#define CN(S,k)  { int et = x##S##k & 7; \
                   float keep = (et == prev##S) ? 1.0f : 0.0f; \
                   prev##S = et; \
                   acc##S = fmaf(__int_as_float(y##S##k), bf2f(w##S##k), acc##S * keep); \
                   unsigned bb = __float_as_uint(acc##S) + 0x8000u; \
                   aggrow##S[et * 64 + lane] = (unsigned short)(bb >> 16); }
#define EF8(S)   EF(S,0) EF(S,1) EF(S,2) EF(S,3) EF(S,4) EF(S,5) EF(S,6) EF(S,7)
#define EFM8(S)  EFM(S,0) EFM(S,1) EFM(S,2) EFM(S,3) EFM(S,4) EFM(S,5) EFM(S,6) EFM(S,7)
#define GF8(S)   GF(S,0) GF(S,1) GF(S,2) GF(S,3) GF(S,4) GF(S,5) GF(S,6) GF(S,7)
#define CN8(S)   CN(S,0) CN(S,1) CN(S,2) CN(S,3) CN(S,4) CN(S,5) CN(S,6) CN(S,7)
    for (int np = 0; np < 2; np++) {
        int lrowA = wave * 4 + np * 2;
        int lrowB = lrowA + 1;
        int nA = __builtin_amdgcn_readfirstlane(n0 + lrowA);
        int nB = nA + 1;
        int j0A = rp4[(size_t)nA * 8], j1A = rp4[(size_t)nA * 8 + 8];
        int j0B = rp4[(size_t)nB * 8], j1B = rp4[(size_t)nB * 8 + 8];
        unsigned short* aggrowA = agg + lrowA * 520;
        unsigned short* aggrowB = agg + lrowB * 520;
        float accA = 0.f, accB = 0.f;
        int prevA = -1, prevB = -1;
        int jA = j0A, jB = j0B;
        while (jA + 8 <= j1A && jB + 8 <= j1B) {
            EF8(A) EF8(B) GF8(A) GF8(B) CN8(A) CN8(B)
            jA += 8; jB += 8;
        }
        while (jA + 8 <= j1A) { EF8(A) GF8(A) CN8(A) jA += 8; }
        while (jB + 8 <= j1B) { EF8(B) GF8(B) CN8(B) jB += 8; }
        {
            int lastA = j1A - 1, lastB = j1B - 1;
            if (((j1A - jA) | (j1B - jB)) > 0) {
                EFM8(A) EFM8(B) GF8(A) GF8(B) CN8(A) CN8(B)
            }
        }
    }
#undef EF
#undef EFM
#undef GF
#undef CN
#undef EF8
#undef EFM8
#undef GF8
#undef CN8
    __syncthreads();
    // ---- MFMA: [16 nodes x 512] @ WpF -> 64 outs; wave covers cols [wave*16, +16)
    int q = lane >> 4, c = lane & 15;
    int o16 = wave * 16;
    f32x4 accd = (f32x4){0.f, 0.f, 0.f, 0.f};
    const bf16x8* B8 = (const bf16x8*)WpF;
#pragma unroll
    for (int s = 0; s < 16; s++) {
        bf16x8 a = *(const bf16x8*)&agg[c * 520 + s * 32 + q * 8];
        bf16x8 bfr = B8[(s * 4 + q) * 64 + o16 + c];
        accd = __builtin_amdgcn_mfma_f32_16x16x32_bf16(a, bfr, accd, 0, 0, 0);
    }
    int col = o16 + c;
    float bia = bias[col];
#pragma unroll
    for (int r = 0; r < 4; r++) {
        int node = n0 + q * 4 + r;
        float v = accd[r] + bia;
        if (mode == 1) {
            v = fmaxf(v, 0.f);
            outb[(size_t)node * 64 + col] = f2bf(v);
        } else {
            outf[(size_t)node * 64 + col] = v;
        }
    }
}

extern "C" void kernel_launch(void* const* d_in, const int* in_sizes, int n_in,
                              void* d_out, int out_size, void* d_ws, size_t ws_size,
                              hipStream_t stream) {
    const int*   feat  = (const int*)d_in[0];
    const int*   src   = (const int*)d_in[1];
    const int*   dst   = (const int*)d_in[2];
    const int*   etype = (const int*)d_in[3];
    const float* norm  = (const float*)d_in[4];
    const float* emb_w = (const float*)d_in[5];
    const float* sm_w  = (const float*)d_in[6];
    const float* sm_b  = (const float*)d_in[7];
    const float* V1    = (const float*)d_in[8];
    const float* comp1 = (const float*)d_in[9];
    const float* b1    = (const float*)d_in[10];
    const float* V2    = (const float*)d_in[11];
    const float* comp2 = (const float*)d_in[12];
    const float* b2    = (const float*)d_in[13];
    float* out = (float*)d_out;

    char* p = (char*)d_ws;
    auto alloc = [&](size_t bytes) { void* q = (void*)p; p += (bytes + 255) & ~(size_t)255; return q; };
    unsigned short* xb   = (unsigned short*)alloc((size_t)N_PAD * 64 * 2);  // 12.8 MB
    unsigned short* hb   = (unsigned short*)alloc((size_t)N_PAD * 64 * 2);  // 12.8 MB
    unsigned short* WpF1 = (unsigned short*)alloc((size_t)KF * HD * 2);     // 64 KB
    unsigned short* WpF2 = (unsigned short*)alloc((size_t)KF * HD * 2);
    unsigned short* smPack = (unsigned short*)alloc(KDIM * HD * 2);         // 32 KB
    int*   cnt    = (int*)alloc((size_t)NBLK_P * NBUCK * 4);                // 803 KB
    int*   boffm  = (int*)alloc((size_t)NBLK_P * NBUCK * 4);                // 803 KB
    int*   btot   = (int*)alloc((size_t)NBUCK * 4);
    int*   bstart = (int*)alloc((size_t)(NBUCK + 1) * 4);
    int*   rowptr8 = (int*)alloc(((size_t)N_NODES * 8 + 1) * 4);            // 3.2 MB
    int2*  staged = (int2*)alloc((size_t)N_EDGES * 8);                      // 12.8 MB
    int2*  edata  = (int2*)alloc((size_t)N_EDGES * 8);                      // 12.8 MB

    k_weights<<<320, 256, 0, stream>>>(V1, comp1, V2, comp2, sm_w, WpF1, WpF2, smPack);

    k_pcount<<<NBLK_P, TPB_P, 0, stream>>>(dst, cnt);
    k_pscan<<<NBUCK_USED, NBLK_P, 0, stream>>>(cnt, boffm, btot);
    k_bscan<<<1, 512, 0, stream>>>(btot, bstart, rowptr8);
    k_pscatter<<<NBLK_P, TPB_P, 0, stream>>>(src, dst, etype, norm, boffm, bstart, staged);
    k_finalize<<<NBUCK_USED, 512, 0, stream>>>(staged, bstart, btot, rowptr8, edata);

    k_sizematch<<<N_PAD / 64, 256, 0, stream>>>(feat, emb_w, smPack, sm_b, xb);

    k_fused<<<N_NODES / 16, 256, 0, stream>>>(xb, rowptr8, edata, WpF1, b1, nullptr, hb, 1);
    k_fused<<<N_NODES / 16, 256, 0, stream>>>(hb, rowptr8, edata, WpF2, b2, out, nullptr, 0);
}